// Round 1
// baseline (588.003 us; speedup 1.0000x reference)
//
#include <hip/hip_runtime.h>
#include <hip/hip_bf16.h>

typedef __bf16 bf16_t;
typedef __bf16 bf16x8 __attribute__((ext_vector_type(8)));
typedef __bf16 bf16x4 __attribute__((ext_vector_type(4)));
typedef float  f32x4  __attribute__((ext_vector_type(4)));

constexpr int K_IC = 4096;   // inner dim
constexpr int N_OC = 4096;   // output channels
constexpr int GROUPS = 32;   // quant groups
// group size = 4096/32 = 128

// ---------------------------------------------------------------------------
// Pass 1: token-wise symmetric int8 quant; qx stored as bf16 (exact: |q|<=127)
// One block per token (row of 4096), 256 threads x 16 elements.
// ---------------------------------------------------------------------------
__global__ __launch_bounds__(256) void quant_kernel(const float* __restrict__ x,
                                                    bf16_t* __restrict__ qx,
                                                    float* __restrict__ x_scales) {
    const int m = blockIdx.x;
    const int tid = threadIdx.x;
    const float4* xr = (const float4*)(x + (size_t)m * K_IC);

    float4 v[4];
    float amax = 0.f;
#pragma unroll
    for (int i = 0; i < 4; ++i) {
        v[i] = xr[i * 256 + tid];
        amax = fmaxf(amax, fmaxf(fmaxf(fabsf(v[i].x), fabsf(v[i].y)),
                                 fmaxf(fabsf(v[i].z), fabsf(v[i].w))));
    }
#pragma unroll
    for (int off = 32; off > 0; off >>= 1)
        amax = fmaxf(amax, __shfl_xor(amax, off, 64));

    __shared__ float wmax[4];
    if ((tid & 63) == 0) wmax[tid >> 6] = amax;
    __syncthreads();
    amax = fmaxf(fmaxf(wmax[0], wmax[1]), fmaxf(wmax[2], wmax[3]));

    const float scale = amax / 127.0f;       // reference x_scales (un-clamped)
    if (tid == 0) x_scales[m] = scale;
    const float sdiv = fmaxf(scale, 1e-8f);  // clamped for the divide only

    bf16x4* qr = (bf16x4*)(qx + (size_t)m * K_IC);
#pragma unroll
    for (int i = 0; i < 4; ++i) {
        float e0 = fminf(fmaxf(rintf(v[i].x / sdiv), -127.f), 127.f);
        float e1 = fminf(fmaxf(rintf(v[i].y / sdiv), -127.f), 127.f);
        float e2 = fminf(fmaxf(rintf(v[i].z / sdiv), -127.f), 127.f);
        float e3 = fminf(fmaxf(rintf(v[i].w / sdiv), -127.f), 127.f);
        bf16x4 o;
        o[0] = (bf16_t)e0; o[1] = (bf16_t)e1; o[2] = (bf16_t)e2; o[3] = (bf16_t)e3;
        qr[i * 256 + tid] = o;
    }
}

// ---------------------------------------------------------------------------
// Pass 2: dequantize W[oc,i] = (qw - zeros[g]) * (base + step*qstep[g]) -> bf16
// One block per oc row, 256 threads x 4 int4-loads (strided, coalesced).
// ---------------------------------------------------------------------------
__global__ __launch_bounds__(256) void dequant_kernel(const int* __restrict__ qweight,
                                                      const int* __restrict__ zeros,
                                                      const int* __restrict__ qstep,
                                                      const float* __restrict__ base_scales,
                                                      const float* __restrict__ step_scales,
                                                      bf16_t* __restrict__ w) {
    const int oc = blockIdx.x;
    const int tid = threadIdx.x;
    const float base = base_scales[oc];
    const float step = step_scales[oc];
    const int4* qwr = (const int4*)(qweight + (size_t)oc * K_IC);
    bf16x4* wr = (bf16x4*)(w + (size_t)oc * K_IC);
#pragma unroll
    for (int i = 0; i < 4; ++i) {
        const int idx = i * 256 + tid;          // int4 index within the row
        const int g = idx >> 5;                 // 32 int4 per group of 128
        const float zp = (float)zeros[oc * GROUPS + g];
        const float sc = base + step * (float)qstep[oc * GROUPS + g];
        int4 a = qwr[idx];
        bf16x4 o;
        o[0] = (bf16_t)(((float)a.x - zp) * sc);
        o[1] = (bf16_t)(((float)a.y - zp) * sc);
        o[2] = (bf16_t)(((float)a.z - zp) * sc);
        o[3] = (bf16_t)(((float)a.w - zp) * sc);
        wr[idx] = o;
    }
}

// ---------------------------------------------------------------------------
// Pass 3: bf16 GEMM (m97 structure). A=[M][K] qx, B=[N][K] W (B^T layout).
// 128x128 block tile, BK=64, 4 waves (2x2), each wave 64x64 via 4x4 MFMA
// 16x16x32 tiles. global_load_lds width=16 staging. Epilogue * x_scale[m].
// ---------------------------------------------------------------------------
#define BM 128
#define BN 128
#define BK 64

__device__ inline void async16(const bf16_t* g, bf16_t* l) {
    __builtin_amdgcn_global_load_lds(
        (const __attribute__((address_space(1))) void*)g,
        (__attribute__((address_space(3))) void*)l,
        16, 0, 0);
}

__global__ __launch_bounds__(256) void gemm_kernel(const bf16_t* __restrict__ A,
                                                   const bf16_t* __restrict__ B,
                                                   const float* __restrict__ x_scales,
                                                   float* __restrict__ out) {
    __shared__ __attribute__((aligned(16))) bf16_t As[BM][BK];
    __shared__ __attribute__((aligned(16))) bf16_t Bs[BN][BK];

    const int tid = threadIdx.x;
    const int lane = tid & 63;
    const int wave = tid >> 6;
    const int waveM = wave >> 1;
    const int waveN = wave & 1;
    const int bn = blockIdx.x;
    const int bm = blockIdx.y;

    f32x4 acc[4][4] = {};

    // staging map: lds byte offset = tid*16 + it*4096 (wave-uniform base + lane*16)
    const int rowOff = tid >> 3;            // 0..31, +32 per it
    const int colOff = (tid & 7) * 8;       // bf16 elements (16B per lane)
    const bf16_t* Aptr = A + (size_t)(bm * BM + rowOff) * K_IC + colOff;
    const bf16_t* Bptr = B + (size_t)(bn * BN + rowOff) * K_IC + colOff;

    const int mrow = waveM * 64 + (lane & 15);
    const int nrow = waveN * 64 + (lane & 15);
    const int kcol = (lane >> 4) * 8;

    for (int kt = 0; kt < K_IC / BK; ++kt) {
        const int k0 = kt * BK;
#pragma unroll
        for (int it = 0; it < 4; ++it) {
            async16(Aptr + (size_t)(it * 32) * K_IC + k0, &As[rowOff + it * 32][colOff]);
            async16(Bptr + (size_t)(it * 32) * K_IC + k0, &Bs[rowOff + it * 32][colOff]);
        }
        __syncthreads();   // compiler emits vmcnt(0) drain before barrier

#pragma unroll
        for (int kk = 0; kk < 2; ++kk) {
            bf16x8 af[4], bfr[4];
#pragma unroll
            for (int i = 0; i < 4; ++i) {
                af[i]  = *(const bf16x8*)&As[mrow + i * 16][kk * 32 + kcol];
                bfr[i] = *(const bf16x8*)&Bs[nrow + i * 16][kk * 32 + kcol];
            }
#pragma unroll
            for (int i = 0; i < 4; ++i)
#pragma unroll
                for (int j = 0; j < 4; ++j)
                    acc[i][j] = __builtin_amdgcn_mfma_f32_16x16x32_bf16(af[i], bfr[j], acc[i][j], 0, 0, 0);
        }
        __syncthreads();
    }

    // epilogue: C/D layout col=lane&15, row=(lane>>4)*4+reg  (m89/m91 verified)
    const int colT = lane & 15;
    const int rgrp = lane >> 4;
#pragma unroll
    for (int i = 0; i < 4; ++i) {
#pragma unroll
        for (int r = 0; r < 4; ++r) {
            const int gr = bm * BM + waveM * 64 + i * 16 + rgrp * 4 + r;
            const float sc = x_scales[gr];
#pragma unroll
            for (int j = 0; j < 4; ++j) {
                const int gc = bn * BN + waveN * 64 + j * 16 + colT;
                out[(size_t)gr * N_OC + gc] = acc[i][j][r] * sc;
            }
        }
    }
}

// ---------------------------------------------------------------------------
extern "C" void kernel_launch(void* const* d_in, const int* in_sizes, int n_in,
                              void* d_out, int out_size, void* d_ws, size_t ws_size,
                              hipStream_t stream) {
    const float* x          = (const float*)d_in[0];
    const int*   qweight    = (const int*)d_in[1];
    const int*   zeros      = (const int*)d_in[2];
    const int*   qstep      = (const int*)d_in[3];
    const float* base_scale = (const float*)d_in[4];
    const float* step_scale = (const float*)d_in[5];
    float* out = (float*)d_out;

    const int M = in_sizes[0] / K_IC;   // 8192 tokens

    char* ws = (char*)d_ws;
    bf16_t* qx = (bf16_t*)ws;                                   // M*K*2   = 64 MiB
    bf16_t* W  = (bf16_t*)(ws + (size_t)M * K_IC * 2);          // N*K*2   = 32 MiB
    float*  xs = (float*)(ws + (size_t)M * K_IC * 2 + (size_t)N_OC * K_IC * 2); // M*4

    quant_kernel<<<M, 256, 0, stream>>>(x, qx, xs);
    dequant_kernel<<<N_OC, 256, 0, stream>>>(qweight, zeros, qstep, base_scale, step_scale, W);

    dim3 grid(N_OC / BN, M / BM);
    gemm_kernel<<<grid, 256, 0, stream>>>(qx, W, xs, out);
}